// Round 8
// baseline (355.461 us; speedup 1.0000x reference)
//
#include <hip/hip_runtime.h>

#define EMB 128
#define NBUC 1024          // coarse buckets: dst >> 7 (128 nodes per bucket)
#define NPART 128          // partition blocks for P1/P2 (128 -> ~49B stream runs in p2)

typedef __attribute__((ext_vector_type(8))) short short8;   // 8 bf16 (4 VGPRs)
typedef __attribute__((ext_vector_type(4))) float f32x4;    // MFMA acc

// ---------------- bf16 helpers ----------------
__device__ __forceinline__ unsigned short f2bf(float f) {
    union { float f; unsigned int i; } v; v.f = f;
    unsigned int x = v.i;
    x += 0x7fffu + ((x >> 16) & 1u);   // round-to-nearest-even
    return (unsigned short)(x >> 16);
}
__device__ __forceinline__ void acc_bf8(uint4 v, float* a) {
    union { unsigned int i; float f; } t;
    t.i = v.x << 16;          a[0] += t.f;
    t.i = v.x & 0xffff0000u;  a[1] += t.f;
    t.i = v.y << 16;          a[2] += t.f;
    t.i = v.y & 0xffff0000u;  a[3] += t.f;
    t.i = v.z << 16;          a[4] += t.f;
    t.i = v.z & 0xffff0000u;  a[5] += t.f;
    t.i = v.w << 16;          a[6] += t.f;
    t.i = v.w & 0xffff0000u;  a[7] += t.f;
}

// ============ CSR build: atomic-light two-level counting sort ============

__global__ __launch_bounds__(256) void p1_hist(const int* __restrict__ dst,
                                               int* __restrict__ BH, int E, int chunk) {
    __shared__ int h[NBUC];
    for (int i = threadIdx.x; i < NBUC; i += 256) h[i] = 0;
    __syncthreads();
    int s = blockIdx.x * chunk;
    int e = min(E, s + chunk);
    for (int i = s + threadIdx.x; i < e; i += 256)
        atomicAdd(&h[dst[i] >> 7], 1);
    __syncthreads();
    for (int i = threadIdx.x; i < NBUC; i += 256)
        BH[blockIdx.x * NBUC + i] = h[i];
}

// Fused middle: block 0 = tot+scan+offs over the 1024 buckets;
// blocks 1..4 = weight pre-swizzle for W1 and W2 (independent work).
__global__ __launch_bounds__(1024) void k_mid(int* __restrict__ BH, int* __restrict__ base,
                                              const float* __restrict__ W1,
                                              const float* __restrict__ W2,
                                              unsigned short* __restrict__ W1s,
                                              unsigned short* __restrict__ W2s, int E) {
    if (blockIdx.x == 0) {
        __shared__ int a[NBUC];
        int t = threadIdx.x;
        int v0 = 0;
        for (int blk = 0; blk < NPART; ++blk) v0 += BH[blk * NBUC + t];
        a[t] = v0;
        __syncthreads();
        for (int off = 1; off < NBUC; off <<= 1) {
            int v = (t >= off) ? a[t - off] : 0;
            __syncthreads();
            a[t] += v;
            __syncthreads();
        }
        int excl = a[t] - v0;
        base[t] = excl;
        if (t == NBUC - 1) base[NBUC] = E;
        int run = excl;
        for (int blk = 0; blk < NPART; ++blk) {
            int* p = &BH[blk * NBUC + t];
            int v = *p;
            *p = run;
            run += v;
        }
    } else {
        // Wb[kk][ct][q][nn][j] = W[kk*32+q*8+j][ct*16+nn] as bf16; lane q*16+nn
        // reads its B-frag for (kk,ct) as one contiguous 16B short8.
        int id = (blockIdx.x - 1) * 8192 + threadIdx.x;
#pragma unroll
        for (int it = 0; it < 8; ++it, id += 1024) {
            int wsel = id >> 14;
            int idx = id & 16383;
            const float* W = wsel ? W2 : W1;
            unsigned short* Ws = wsel ? W2s : W1s;
            int k = idx >> 7, n = idx & 127;
            int kk = k >> 5, q = (k >> 3) & 3, j = k & 7;
            int ct = n >> 4, nn = n & 15;
            int didx = ((((kk * 8 + ct) * 4 + q) * 16 + nn) << 3) + j;
            Ws[didx] = f2bf(W[idx]);
        }
    }
}

__global__ __launch_bounds__(256) void p2_scatter(const int* __restrict__ src,
                                                  const int* __restrict__ dst,
                                                  const int* __restrict__ BH,
                                                  int* __restrict__ part,
                                                  int E, int chunk) {
    __shared__ int cnt[NBUC];
    for (int i = threadIdx.x; i < NBUC; i += 256)
        cnt[i] = BH[blockIdx.x * NBUC + i];
    __syncthreads();
    int s = blockIdx.x * chunk;
    int e = min(E, s + chunk);
    for (int i = s + threadIdx.x; i < e; i += 256) {
        int d = dst[i];
        int pos = atomicAdd(&cnt[d >> 7], 1);
        part[pos] = src[i] | ((d & 127) << 17);   // src < 2^17, local node in [0,128)
    }
}

__global__ __launch_bounds__(256) void p3_csr(const int* __restrict__ part,
                                              const int* __restrict__ base,
                                              int* __restrict__ R, int* __restrict__ adj,
                                              float* __restrict__ dis, int N, int E) {
    __shared__ int hist[128];
    __shared__ int sc[128];
    __shared__ int cnt[128];
    int b = blockIdx.x;
    int n0 = b * 128;
    int nn = min(128, N - n0);
    int s = base[b], e = base[b + 1];
    int t = threadIdx.x;

    if (t < 128) hist[t] = 0;
    __syncthreads();
    for (int i = s + t; i < e; i += 256)
        atomicAdd(&hist[part[i] >> 17], 1);
    __syncthreads();

    if (t < 128) sc[t] = hist[t];
    __syncthreads();
    for (int off = 1; off < 128; off <<= 1) {
        int v = 0;
        if (t < 128 && t >= off) v = sc[t - off];
        __syncthreads();
        if (t < 128) sc[t] += v;
        __syncthreads();
    }
    if (t < 128) {
        int excl = sc[t] - hist[t];
        cnt[t] = excl;
        if (t < nn) {
            R[n0 + t] = s + excl;
            dis[n0 + t] = rsqrtf((float)hist[t] + 1.0f);   // +1 self-loop
        }
    }
    if (b == 0 && t == 0) R[N] = E;
    __syncthreads();

    for (int i = s + t; i < e; i += 256) {
        int p = part[i];
        int pos = atomicAdd(&cnt[p >> 17], 1);
        adj[s + pos] = p & 0x1FFFF;
    }
}

// ---------------- MFMA GEMM: Y[n] = bf16((X[n] @ W) * dis[n]) ----------------
// 64 nodes/block, 16/wave; K=128 as 4 steps of mfma_f32_16x16x32_bf16.
// A: m=lane&15, k=q*8+j; B: n=lane&15, k=q*8+j; D: n=lane&15, m=q*4+reg.
// In-place safe for layer 2 (X==Y): block touches only its own 64 rows; all
// A reads precede the __syncthreads() before any store.
template <bool XBF16>
__global__ __launch_bounds__(256) void k_gemm_mfma(
    const void* Xv, const unsigned short* __restrict__ Wsw,
    const float* __restrict__ dis, unsigned short* Y, int N)
{
    __shared__ __align__(16) unsigned short lds[16384];   // 32 KB: W frags, then out-stage

    {
        const uint4* srcp = (const uint4*)Wsw;
        uint4* dstp = (uint4*)lds;
        for (int i = threadIdx.x; i < 2048; i += 256) dstp[i] = srcp[i];
    }
    __syncthreads();

    const int wave = threadIdx.x >> 6;
    const int lane = threadIdx.x & 63;
    const int q = lane >> 4, nn = lane & 15;
    const int row0 = blockIdx.x * 64 + wave * 16;
    const int arow = row0 + nn;
    const int arc = arow < N ? arow : N - 1;

    f32x4 acc[8];
#pragma unroll
    for (int ct = 0; ct < 8; ++ct) acc[ct] = (f32x4){0.f, 0.f, 0.f, 0.f};

#pragma unroll
    for (int kk = 0; kk < 4; ++kk) {
        short8 af;
        if (XBF16) {
            af = *(const short8*)((const unsigned short*)Xv + (size_t)arc * EMB + kk * 32 + q * 8);
        } else {
            const float* xp = (const float*)Xv + (size_t)arc * EMB + kk * 32 + q * 8;
            float4 u0 = *(const float4*)xp;
            float4 u1 = *(const float4*)(xp + 4);
            af[0] = (short)f2bf(u0.x); af[1] = (short)f2bf(u0.y);
            af[2] = (short)f2bf(u0.z); af[3] = (short)f2bf(u0.w);
            af[4] = (short)f2bf(u1.x); af[5] = (short)f2bf(u1.y);
            af[6] = (short)f2bf(u1.z); af[7] = (short)f2bf(u1.w);
        }
#pragma unroll
        for (int ct = 0; ct < 8; ++ct) {
            short8 bf = ((const short8*)lds)[(kk * 8 + ct) * 64 + lane];
            acc[ct] = __builtin_amdgcn_mfma_f32_16x16x32_bf16(af, bf, acc[ct], 0, 0, 0);
        }
    }

    __syncthreads();   // W reads + all A-frag (X) reads complete block-wide

    float dv[4];
#pragma unroll
    for (int r = 0; r < 4; ++r) {
        int gm = row0 + q * 4 + r;
        dv[r] = dis[gm < N ? gm : N - 1];
    }
#pragma unroll
    for (int ct = 0; ct < 8; ++ct) {
#pragma unroll
        for (int r = 0; r < 4; ++r) {
            int ml = wave * 16 + q * 4 + r;
            lds[ml * 136 + ct * 16 + nn] = f2bf(acc[ct][r] * dv[r]);
        }
    }
    __syncthreads();

    const int rbase = blockIdx.x * 64;
    for (int i = threadIdx.x; i < 1024; i += 256) {
        int row = i >> 4, off = i & 15;
        int grow = rbase + row;
        if (grow < N) {
            uint4 v = *(const uint4*)(lds + row * 136 + off * 8);
            *((uint4*)(Y + (size_t)grow * EMB) + off) = v;
        }
    }
}

// ---------------- fused gather + normalize + bias (+relu) ----------------
// 16 lanes per node; lane covers 8 consecutive cols (16B uint4 bf16 loads).
// Out[n] = act(dis[n] * (Y[n] + sum_{e in CSR row n} Y[adj[e]]) + b)
template <bool RELU, bool BF16OUT>
__global__ __launch_bounds__(256) void k_gather_finalize(
    const int* __restrict__ R, const int* __restrict__ adj,
    const unsigned short* __restrict__ Y, const float* __restrict__ dis,
    const float* __restrict__ bias, void* __restrict__ Outv, int N)
{
    int t = blockIdx.x * 256 + threadIdx.x;
    int n = t >> 4;
    if (n >= N) return;
    int j = (t & 15) * 8;

    int rs = R[n], re = R[n + 1];

    float a[8] = {0.f, 0.f, 0.f, 0.f, 0.f, 0.f, 0.f, 0.f};
    uint4 sv = *(const uint4*)(Y + (size_t)n * EMB + j);
    acc_bf8(sv, a);

    int e = rs;
    for (; e + 3 < re; e += 4) {
        int s0 = adj[e], s1 = adj[e + 1], s2 = adj[e + 2], s3 = adj[e + 3];
        uint4 v0 = *(const uint4*)(Y + (size_t)s0 * EMB + j);
        uint4 v1 = *(const uint4*)(Y + (size_t)s1 * EMB + j);
        uint4 v2 = *(const uint4*)(Y + (size_t)s2 * EMB + j);
        uint4 v3 = *(const uint4*)(Y + (size_t)s3 * EMB + j);
        acc_bf8(v0, a);
        acc_bf8(v1, a);
        acc_bf8(v2, a);
        acc_bf8(v3, a);
    }
    for (; e < re; ++e) {
        uint4 v0 = *(const uint4*)(Y + (size_t)adj[e] * EMB + j);
        acc_bf8(v0, a);
    }

    float dv = dis[n];
    float4 b0 = *(const float4*)(bias + j);
    float4 b1 = *(const float4*)(bias + j + 4);
    float o[8];
    o[0] = dv * a[0] + b0.x; o[1] = dv * a[1] + b0.y;
    o[2] = dv * a[2] + b0.z; o[3] = dv * a[3] + b0.w;
    o[4] = dv * a[4] + b1.x; o[5] = dv * a[5] + b1.y;
    o[6] = dv * a[6] + b1.z; o[7] = dv * a[7] + b1.w;
    if (RELU) {
#pragma unroll
        for (int i = 0; i < 8; ++i) o[i] = fmaxf(o[i], 0.f);
    }
    if (BF16OUT) {
        uint4 p;
        p.x = (unsigned int)f2bf(o[0]) | ((unsigned int)f2bf(o[1]) << 16);
        p.y = (unsigned int)f2bf(o[2]) | ((unsigned int)f2bf(o[3]) << 16);
        p.z = (unsigned int)f2bf(o[4]) | ((unsigned int)f2bf(o[5]) << 16);
        p.w = (unsigned int)f2bf(o[6]) | ((unsigned int)f2bf(o[7]) << 16);
        *(uint4*)((unsigned short*)Outv + (size_t)n * EMB + j) = p;
    } else {
        float* op = (float*)Outv + (size_t)n * EMB + j;
        *(float4*)op = make_float4(o[0], o[1], o[2], o[3]);
        *(float4*)(op + 4) = make_float4(o[4], o[5], o[6], o[7]);
    }
}

extern "C" void kernel_launch(void* const* d_in, const int* in_sizes, int n_in,
                              void* d_out, int out_size, void* d_ws, size_t ws_size,
                              hipStream_t stream) {
    const int* ei = (const int*)d_in[0];
    const int E = in_sizes[0] / 2;
    const float* emb = (const float*)d_in[2];
    const int N = in_sizes[2] / EMB;
    const float* W1 = (const float*)d_in[3];
    const float* b1 = (const float*)d_in[4];
    const float* W2 = (const float*)d_in[5];
    const float* b2 = (const float*)d_in[6];
    float* out = (float*)d_out;

    const int* src = ei;
    const int* dstp = ei + E;

    // ws: dis | R | base | adj | W1s | W2s | Hb (part/BH overlay Hb; both dead
    // before gather1 writes Hb).  Y1b lives in d_out bytes (dead before
    // gather2 writes d_out f32).  Total ~33 MB.
    char* w = (char*)d_ws;
    auto take = [&](size_t bytes) { char* p = w; w += (bytes + 511) & ~(size_t)511; return p; };
    float* dis  = (float*)take((size_t)N * 4);
    int*   R    = (int*)  take((size_t)(N + 1) * 4);
    int*   base = (int*)  take((size_t)(NBUC + 1) * 4);
    int*   adj  = (int*)  take((size_t)E * 4);
    unsigned short* W1s = (unsigned short*)take((size_t)EMB * EMB * 2);
    unsigned short* W2s = (unsigned short*)take((size_t)EMB * EMB * 2);
    unsigned short* Hb  = (unsigned short*)take((size_t)N * EMB * 2);
    int*   part = (int*)Hb;                                  // overlay (dead before Hb)
    int*   BH   = (int*)((char*)Hb + (((size_t)E * 4 + 511) & ~(size_t)511));
    unsigned short* Y1b = (unsigned short*)d_out;            // overlay in d_out

    const int NB = (N + 127) / 128;
    const int chunk = (E + NPART - 1) / NPART;
    const int gM = (N + 63) / 64;            // MFMA gemm blocks
    const int gG = (N * 16 + 255) / 256;     // gather blocks (16 lanes/node)

    // --- CSR + dis + weight-swizzle (shared by both layers) ---
    p1_hist   <<<NPART, 256, 0, stream>>>(dstp, BH, E, chunk);
    k_mid     <<<5, 1024, 0, stream>>>(BH, base, W1, W2, W1s, W2s, E);
    p2_scatter<<<NPART, 256, 0, stream>>>(src, dstp, BH, part, E, chunk);
    p3_csr    <<<NB, 256, 0, stream>>>(part, base, R, adj, dis, N, E);

    // --- layer 1: Y1b = bf16((emb@W1)*dis); Hb = bf16(relu(dis*(gather+self)+b1)) ---
    k_gemm_mfma<false><<<gM, 256, 0, stream>>>(emb, W1s, dis, Y1b, N);
    k_gather_finalize<true, true><<<gG, 256, 0, stream>>>(R, adj, Y1b, dis, b1, Hb, N);

    // --- layer 2: Hb = bf16((Hb@W2)*dis) in-place; out = dis*(gather+self)+b2 ---
    k_gemm_mfma<true><<<gM, 256, 0, stream>>>(Hb, W2s, dis, Hb, N);
    k_gather_finalize<false, false><<<gG, 256, 0, stream>>>(R, adj, Hb, dis, b2, out, N);
}